// Round 6
// baseline (215.961 us; speedup 1.0000x reference)
//
#include <hip/hip_runtime.h>

// SOM loss, MI355X. Dims fixed: B=4096, D=1024, m=n=128, T=100.
// ws layout:
//   Xb   bf16[4096][1024]        @ 0
//   Wb   bf16[16384][1024]       @ 8388608
//   x2   f32[4096]               @ 41943040
//   w2   f32[16384]              @ 41959424
//   d2   bf16[4096][16384]       @ 42024960
//   pmin f32[4096][128]          @ 176242688   (2 MB)
//   pidx i32[4096][128]          @ 178339840   (2 MB)
//   lossb f32[4096]              @ 180453376

typedef __attribute__((ext_vector_type(8))) short short8;
typedef __attribute__((ext_vector_type(4))) float f32x4;
typedef unsigned short ushort_t;

#define B_ROWS 4096
#define DIM    1024
#define MN     16384
#define NJB    128

__device__ static inline ushort_t f32_to_bf16(float f) {
    unsigned u = __float_as_uint(f);
    u = (u + 0x7FFFu + ((u >> 16) & 1u)) >> 16;   // RTN-even
    return (ushort_t)u;
}
__device__ static inline float bf16_to_f32(ushort_t h) {
    return __uint_as_float(((unsigned)h) << 16);
}
__device__ static inline void gload_lds16(const void* g, void* l) {
    __builtin_amdgcn_global_load_lds(
        (const __attribute__((address_space(1))) unsigned*)g,
        (__attribute__((address_space(3))) unsigned*)l, 16, 0, 0);
}

// ---------- Kernel 1: f32 -> bf16 conversion + row sum-of-squares ----------
__global__ __launch_bounds__(256) void k_convert(
    const float* __restrict__ X, const float* __restrict__ W,
    ushort_t* __restrict__ Xb, ushort_t* __restrict__ Wb,
    float* __restrict__ x2, float* __restrict__ w2) {
    int row  = blockIdx.x * 4 + (threadIdx.x >> 6);
    int lane = threadIdx.x & 63;
    const float4* src;
    ushort4* dst;
    float* sq;
    if (row < B_ROWS) {
        src = (const float4*)(X + (size_t)row * DIM);
        dst = (ushort4*)(Xb + (size_t)row * DIM);
        sq  = x2 + row;
    } else {
        int r2 = row - B_ROWS;
        src = (const float4*)(W + (size_t)r2 * DIM);
        dst = (ushort4*)(Wb + (size_t)r2 * DIM);
        sq  = w2 + r2;
    }
    float s = 0.f;
    #pragma unroll
    for (int c = 0; c < 4; ++c) {
        float4 v = src[c * 64 + lane];
        s += v.x * v.x + v.y * v.y + v.z * v.z + v.w * v.w;
        ushort4 o = { f32_to_bf16(v.x), f32_to_bf16(v.y),
                      f32_to_bf16(v.z), f32_to_bf16(v.w) };
        dst[c * 64 + lane] = o;
    }
    #pragma unroll
    for (int d = 1; d < 64; d <<= 1) s += __shfl_xor(s, d);
    if (lane == 0) *sq = s;
}

// ---------- Kernel 2: 256x128-tile GEMM, 64x64 waves, 2 blocks/CU ----------
// 512 thr = 8 waves (4M x 2N), each 64x64 (acc = 64 f32/lane). BK=32.
// LDS: 2 dbuf x 24KB (A 256x32 + B 128x32 bf16), rows packed pairwise into
// 128B composite rows, XOR-swizzled ((crow&7)<<4) -> 2-way (free) ds_read_b128.
// Occupancy target: 2 blocks/CU (16 waves) for TLP-based latency hiding.
__global__ __launch_bounds__(512, 4) void k_gemm(
    const ushort_t* __restrict__ Xb, const ushort_t* __restrict__ Wb,
    const float* __restrict__ x2, const float* __restrict__ w2,
    ushort_t* __restrict__ d2, float* __restrict__ pmin, int* __restrict__ pidx) {
    __shared__ __attribute__((aligned(1024))) unsigned char ldsb[65536];

    const int tid  = threadIdx.x;
    const int lane = tid & 63;
    const int w    = tid >> 6;
    const int wrM  = w >> 1;      // 0..3  (X-row quarter)
    const int wcN  = w & 1;       // 0..1  (W-col half)
    const int lc   = lane & 15;
    const int lr16 = lane >> 4;   // 0..3

    // XCD-bijective block swizzle (2048 % 8 == 0)
    const int bid = blockIdx.x;
    const int swz = (bid & 7) * 256 + (bid >> 3);
    const int tn  = swz >> 4;     // 0..127  W-tile (128 cols each)
    const int tm  = swz & 15;     // 0..15   X-tile (256 rows each)

    const size_t aRow = (size_t)tm * 256;
    const size_t bRow = (size_t)tn * 128;

    // staging precompute: 3 chunks of 16B/thread (A 16KB = 2 chunks, B 8KB = 1)
    // composite layout: crow = p>>7 holds logical rows {2*crow, 2*crow+1};
    // physical col7 -> logical col = col7 ^ ((crow&7)<<4); lcol<64 -> row 2crow,
    // lcol>=64 -> row 2crow+1; k-elem = (lcol&63)>>1.
    const ushort_t* srcA0; const ushort_t* srcA1; const ushort_t* srcB0;
    {
        int p, crow, lcol;
        p = tid * 16; crow = p >> 7; lcol = (p & 127) ^ ((crow & 7) << 4);
        srcA0 = Xb + (aRow + crow * 2 + (lcol >> 6)) * DIM + ((lcol & 63) >> 1);
        p = 8192 + tid * 16; crow = p >> 7; lcol = (p & 127) ^ ((crow & 7) << 4);
        srcA1 = Xb + (aRow + crow * 2 + (lcol >> 6)) * DIM + ((lcol & 63) >> 1);
        p = tid * 16; crow = p >> 7; lcol = (p & 127) ^ ((crow & 7) << 4);
        srcB0 = Wb + (bRow + crow * 2 + (lcol >> 6)) * DIM + ((lcol & 63) >> 1);
    }

    #define STAGE(kt, buf) do {                                                  \
        gload_lds16(srcA0 + (kt) * 32, ldsb + (buf) * 24576 + tid * 16);         \
        gload_lds16(srcA1 + (kt) * 32, ldsb + (buf) * 24576 + 8192 + tid * 16);  \
        gload_lds16(srcB0 + (kt) * 32, ldsb + (buf) * 24576 + 16384 + tid * 16); \
    } while (0)

    // frag read tail: logical row = base+lc, kslice bytes lr16*16
    const int tailC = (lc >> 1) * 128 +
                      ((((lc & 1) << 6) + (lr16 << 4)) ^ (((lc >> 1) & 7) << 4));
    const int xbase = wrM * 4096;           // (wrM*64)*64 bytes
    const int wbase = 16384 + wcN * 4096;

    short8 WF[4], XF[4];
    f32x4  acc[4][4];
    #pragma unroll
    for (int i = 0; i < 4; ++i)
        #pragma unroll
        for (int j = 0; j < 4; ++j) acc[i][j] = (f32x4)0.f;

    #define BAR() __builtin_amdgcn_s_barrier()
    #define SCB() __builtin_amdgcn_sched_barrier(0)

    // prologue: T0 -> buf0, T1 -> buf1
    STAGE(0, 0);
    STAGE(1, 1);
    asm volatile("s_waitcnt vmcnt(3)" ::: "memory");   // T0 landed
    SCB();
    BAR();

    for (int kt = 0; kt < 32; ++kt) {
        const int bb = (kt & 1) * 24576;
        #pragma unroll
        for (int n = 0; n < 4; ++n)
            WF[n] = *(const short8*)(ldsb + bb + wbase + n * 1024 + tailC);
        #pragma unroll
        for (int m = 0; m < 4; ++m)
            XF[m] = *(const short8*)(ldsb + bb + xbase + m * 1024 + tailC);
        asm volatile("s_waitcnt lgkmcnt(0)" ::: "memory");
        SCB();
        __builtin_amdgcn_s_setprio(1);
        #pragma unroll
        for (int m = 0; m < 4; ++m)
            #pragma unroll
            for (int n = 0; n < 4; ++n)
                acc[m][n] = __builtin_amdgcn_mfma_f32_16x16x32_bf16(
                    WF[n], XF[m], acc[m][n], 0, 0, 0);
        __builtin_amdgcn_s_setprio(0);
        SCB();
        BAR();                               // all waves' reads of bb drained
        if (kt < 30) {
            STAGE(kt + 2, kt & 1);
            asm volatile("s_waitcnt vmcnt(3)" ::: "memory");  // kt+1 landed
            SCB();
            BAR();
        } else if (kt == 30) {
            asm volatile("s_waitcnt vmcnt(0)" ::: "memory");  // kt 31 landed
            SCB();
            BAR();
        }
    }

    // ---- epilogue: d2 = x2 - 2*dot + w2, LDS-transposed coalesced stores ----
    // per-wave 8KB region: [mi:4][lc:16][128B], col-byte XOR ((lc&7)<<4)
    unsigned char* wls = ldsb + w * 8192;
    const int smask = (lc & 7) << 4;
    const int colw = tn * 128 + wcN * 64;
    const int rowbase = tm * 256 + wrM * 64;
    float4 w2q[4];
    #pragma unroll
    for (int ni = 0; ni < 4; ++ni)
        w2q[ni] = *(const float4*)(w2 + colw + ni * 16 + lr16 * 4);

    float mnA[4]; int ixA[4];
    #pragma unroll
    for (int mi = 0; mi < 4; ++mi) {
        const int row = rowbase + mi * 16 + lc;
        const float xx = x2[row];
        float mn = __builtin_inff(); int ix = 0x7fffffff;
        #pragma unroll
        for (int ni = 0; ni < 4; ++ni) {
            float dv[4];
            ushort4 st;
            #pragma unroll
            for (int rg = 0; rg < 4; ++rg) {
                dv[rg] = xx - 2.f * acc[mi][ni][rg] + w2q[ni][rg];
                st[rg] = (unsigned short)f32_to_bf16(dv[rg]);
            }
            *(ushort4*)(wls + mi * 2048 + lc * 128
                        + ((ni * 32 + lr16 * 8) ^ smask)) = st;
            #pragma unroll
            for (int rg = 0; rg < 4; ++rg) {
                const int cand = colw + ni * 16 + lr16 * 4 + rg;
                if (dv[rg] < mn || (dv[rg] == mn && cand < ix)) { mn = dv[rg]; ix = cand; }
            }
        }
        #pragma unroll
        for (int d = 16; d < 64; d <<= 1) {
            float om = __shfl_xor(mn, d);
            int   oi = __shfl_xor(ix, d);
            if (om < mn || (om == mn && oi < ix)) { mn = om; ix = oi; }
        }
        mnA[mi] = mn; ixA[mi] = ix;
    }
    asm volatile("s_waitcnt lgkmcnt(0)" ::: "memory");  // wave-private LDS WAR
    SCB();
    // read back transposed: 8 lanes x 16B = 128B contiguous per row
    #pragma unroll
    for (int j = 0; j < 8; ++j) {
        const int rl  = j * 8 + (lane >> 3);      // row_local 0..63
        const int ii  = rl >> 4, lcr = rl & 15;
        const int cb  = (lane & 7) * 16;
        short8 v = *(const short8*)(wls + ii * 2048 + lcr * 128
                                    + (cb ^ ((lcr & 7) << 4)));
        *(short8*)((char*)(d2 + (size_t)(rowbase + rl) * MN + colw) + cb) = v;
    }
    __syncthreads();
    // per-row argmin partials across the 2 N-waves
    float* smin = (float*)ldsb;            // [256][2]
    int*   sidx = (int*)(ldsb + 2048);     // [256][2]
    if (lane < 16) {
        #pragma unroll
        for (int mi = 0; mi < 4; ++mi) {
            const int rloc = wrM * 64 + mi * 16 + lane;
            smin[rloc * 2 + wcN] = mnA[mi];
            sidx[rloc * 2 + wcN] = ixA[mi];
        }
    }
    __syncthreads();
    if (tid < 256) {
        float m0 = smin[tid * 2];     int i0 = sidx[tid * 2];
        float m1 = smin[tid * 2 + 1]; int i1 = sidx[tid * 2 + 1];
        bool take1 = (m1 < m0) || (m1 == m0 && i1 < i0);
        const int row = tm * 256 + tid;
        pmin[(size_t)row * NJB + tn] = take1 ? m1 : m0;
        pidx[(size_t)row * NJB + tn] = take1 ? i1 : i0;
    }
    #undef STAGE
    #undef BAR
    #undef SCB
}

// ---------- Kernel 3: fused argmin-finish + influence-weighted row sum ----------
__global__ __launch_bounds__(256) void k_loss(
    const ushort_t* __restrict__ d2, const float* __restrict__ pmin,
    const int* __restrict__ pidx, float* __restrict__ lossb) {
    __shared__ float etab[255];
    __shared__ float red[4];
    __shared__ int bmu_s;
    int t = threadIdx.x;
    if (t < 255) etab[t] = __expf(-(float)(t * t) * 1e-4f);  // exp(-r^2/T^2), T=100
    int row = blockIdx.x;
    if (t < 64) {
        float m0 = pmin[(size_t)row * NJB + t];
        int   i0 = pidx[(size_t)row * NJB + t];
        float m1 = pmin[(size_t)row * NJB + t + 64];
        int   i1 = pidx[(size_t)row * NJB + t + 64];
        if (m1 < m0 || (m1 == m0 && i1 < i0)) { m0 = m1; i0 = i1; }
        #pragma unroll
        for (int d = 1; d < 64; d <<= 1) {
            float om = __shfl_xor(m0, d);
            int   oi = __shfl_xor(i0, d);
            if (om < m0 || (om == m0 && oi < i0)) { m0 = om; i0 = oi; }
        }
        if (t == 0) bmu_s = i0;
    }
    __syncthreads();
    int bl = bmu_s;
    int bi = bl >> 7, bj = bl & 127;
    const ushort_t* dr = d2 + (size_t)row * MN;
    float s = 0.f;
    #pragma unroll
    for (int c = 0; c < 8; ++c) {
        int j = c * 2048 + t * 8;
        short8 v = *(const short8*)&dr[j];
        int di = abs((j >> 7) - bi);
        int jc = j & 127;
        #pragma unroll
        for (int u = 0; u < 8; ++u) {
            int mh = di + abs(jc + u - bj);
            s += bf16_to_f32((ushort_t)v[u]) * etab[mh];
        }
    }
    #pragma unroll
    for (int d = 1; d < 64; d <<= 1) s += __shfl_xor(s, d);
    if ((t & 63) == 0) red[t >> 6] = s;
    __syncthreads();
    if (t == 0) lossb[row] = red[0] + red[1] + red[2] + red[3];
}

// ---------- Kernel 4: final deterministic reduce ----------
__global__ __launch_bounds__(256) void k_final(
    const float* __restrict__ lossb, float* __restrict__ out) {
    __shared__ float red[4];
    int t = threadIdx.x;
    float s = 0.f;
    #pragma unroll
    for (int k = 0; k < 16; ++k) s += lossb[t + k * 256];
    #pragma unroll
    for (int d = 1; d < 64; d <<= 1) s += __shfl_xor(s, d);
    if ((t & 63) == 0) red[t >> 6] = s;
    __syncthreads();
    if (t == 0) out[0] = (red[0] + red[1] + red[2] + red[3]) * (1.0f / 128.0f);
}

extern "C" void kernel_launch(void* const* d_in, const int* in_sizes, int n_in,
                              void* d_out, int out_size, void* d_ws, size_t ws_size,
                              hipStream_t stream) {
    const float* X = (const float*)d_in[0];
    const float* W = (const float*)d_in[1];
    unsigned char* ws = (unsigned char*)d_ws;
    ushort_t* Xb   = (ushort_t*)(ws);
    ushort_t* Wb   = (ushort_t*)(ws + 8388608);
    float*    x2   = (float*)(ws + 41943040);
    float*    w2   = (float*)(ws + 41959424);
    ushort_t* d2   = (ushort_t*)(ws + 42024960);
    float*    pmin = (float*)(ws + 176242688);
    int*      pidx = (int*)(ws + 178339840);
    float*    lossb= (float*)(ws + 180453376);

    k_convert<<<5120, 256, 0, stream>>>(X, W, Xb, Wb, x2, w2);
    k_gemm<<<2048, 512, 0, stream>>>(Xb, Wb, x2, w2, d2, pmin, pidx);
    k_loss<<<4096, 256, 0, stream>>>(d2, pmin, pidx, lossb);
    k_final<<<1, 256, 0, stream>>>(lossb, (float*)d_out);
}